// Round 4
// baseline (309.162 us; speedup 1.0000x reference)
//
#include <hip/hip_runtime.h>
#include <hip/hip_bf16.h>
#include <type_traits>

// Problem constants: N=4, Sq=2048, Skv=4096, E=1024, H=16, D=64, C=512
// Float tensors are FP32 in global; mask int32; output fp32.
#define NB   4
#define SQ   2048
#define SKV  4096
#define EMB  1024
#define CDIM 512

typedef __attribute__((ext_vector_type(8))) short short8;
typedef __attribute__((ext_vector_type(4))) float f32x4;

__device__ __forceinline__ float b2f(ushort u) {
    union { unsigned int i; float f; } v;
    v.i = ((unsigned int)u) << 16;
    return v.f;
}
__device__ __forceinline__ ushort f2b(float f) {
    union { float f; unsigned int i; } v; v.f = f;
    unsigned int x = v.i;
    return (ushort)((x + 0x7fffu + ((x >> 16) & 1u)) >> 16);   // RNE
}
__device__ __forceinline__ short8 pack_bf16x8(float4 a, float4 b) {
    union { short8 s; ushort u[8]; } r;
    r.u[0] = f2b(a.x); r.u[1] = f2b(a.y); r.u[2] = f2b(a.z); r.u[3] = f2b(a.w);
    r.u[4] = f2b(b.x); r.u[5] = f2b(b.y); r.u[6] = f2b(b.z); r.u[7] = f2b(b.w);
    return r.s;
}

// async global->LDS, 16B per lane; LDS dest = wave-uniform base + lane*16
__device__ __forceinline__ void glds16(const ushort* gp, ushort* lp) {
    __builtin_amdgcn_global_load_lds(
        (const __attribute__((address_space(1))) unsigned int*)gp,
        (__attribute__((address_space(3))) unsigned int*)lp,
        16, 0, 0);
}

// ---------------------------------------------------------------------------
// f32 -> bf16 bulk convert (memory-bound)
// ---------------------------------------------------------------------------
__global__ __launch_bounds__(256)
void cvt_f32_bf16(const float* __restrict__ in, ushort* __restrict__ out, int n4)
{
    const int i = blockIdx.x * 256 + threadIdx.x;
    if (i < n4) {
        float4 v = ((const float4*)in)[i];
        ushort4 o;
        o.x = f2b(v.x); o.y = f2b(v.y); o.z = f2b(v.z); o.w = f2b(v.w);
        ((ushort4*)out)[i] = o;
    }
}

// ---------------------------------------------------------------------------
// Pure-bf16 GEMM (m97 structure): C[m,n] = sum_k A[m,k]*B[n,k] + bias[n]
// 128x128 tile, BK=32, 4 waves x (4x4) mfma_f32_16x16x32_bf16,
// staging via global_load_lds width=16.  (unchanged from round 3 — passed)
// ---------------------------------------------------------------------------
template <typename OT>
__global__ __launch_bounds__(256)
void gemm_bt_bias(const ushort* __restrict__ A, const ushort* __restrict__ B,
                  const float* __restrict__ bias, OT* __restrict__ C,
                  int M, int Nn, int K)
{
    __shared__ __attribute__((aligned(16))) ushort As[128 * 32];
    __shared__ __attribute__((aligned(16))) ushort Bs[128 * 32];

    const int tid  = threadIdx.x;
    const int wave = tid >> 6;
    const int lane = tid & 63;
    const int quad = lane >> 4;
    const int l16  = lane & 15;
    const int wr   = wave >> 1;
    const int wc   = wave & 1;

    const long mBase = (long)blockIdx.x * 128;
    const long nBase = (long)blockIdx.y * 128;

    const ushort* Ablk = A + mBase * K;
    const ushort* Bblk = B + nBase * K;

    const int lr = lane >> 2;
    const int lc = (lane & 3) * 8;
    const int c0 = wave * 2, c1 = wave * 2 + 1;
    const ushort* aG0 = Ablk + (long)(c0 * 16 + lr) * K + lc;
    const ushort* aG1 = Ablk + (long)(c1 * 16 + lr) * K + lc;
    const ushort* bG0 = Bblk + (long)(c0 * 16 + lr) * K + lc;
    const ushort* bG1 = Bblk + (long)(c1 * 16 + lr) * K + lc;
    ushort* aL0 = As + c0 * 512;
    ushort* aL1 = As + c1 * 512;
    ushort* bL0 = Bs + c0 * 512;
    ushort* bL1 = Bs + c1 * 512;

    f32x4 acc[4][4];
#pragma unroll
    for (int i = 0; i < 4; ++i)
#pragma unroll
        for (int j = 0; j < 4; ++j)
            acc[i][j] = (f32x4){0.f, 0.f, 0.f, 0.f};

    for (int k0 = 0; k0 < K; k0 += 32) {
        __syncthreads();
        glds16(aG0 + k0, aL0);
        glds16(aG1 + k0, aL1);
        glds16(bG0 + k0, bL0);
        glds16(bG1 + k0, bL1);
        __syncthreads();

        short8 af[4], bfr[4];
#pragma unroll
        for (int mt = 0; mt < 4; ++mt)
            af[mt] = *(const short8*)(As + (wr * 64 + mt * 16 + l16) * 32 + quad * 8);
#pragma unroll
        for (int nt = 0; nt < 4; ++nt)
            bfr[nt] = *(const short8*)(Bs + (wc * 64 + nt * 16 + l16) * 32 + quad * 8);

#pragma unroll
        for (int mt = 0; mt < 4; ++mt)
#pragma unroll
            for (int nt = 0; nt < 4; ++nt)
                acc[mt][nt] = __builtin_amdgcn_mfma_f32_16x16x32_bf16(
                    af[mt], bfr[nt], acc[mt][nt], 0, 0, 0);
    }

#pragma unroll
    for (int mt = 0; mt < 4; ++mt) {
#pragma unroll
        for (int nt = 0; nt < 4; ++nt) {
            const long n = nBase + wc * 64 + nt * 16 + l16;
            const float bv = bias[n];
#pragma unroll
            for (int r = 0; r < 4; ++r) {
                const long m = mBase + wr * 64 + mt * 16 + quad * 4 + r;
                if constexpr (std::is_same<OT, float>::value)
                    C[m * Nn + n] = acc[mt][nt][r] + bv;
                else
                    C[m * Nn + n] = f2b(acc[mt][nt][r] + bv);
            }
        }
    }
}

// ---------------------------------------------------------------------------
// Attention: ONE WAVE per (n, s2) position; 4 positions per 256-thr block.
// Zero LDS, zero barriers.
//   scores: D = cq(16x64) . k^T  via 2x mfma_f32_16x16x32_bf16.
//     A-frag: cq[m=l16][d=c*32+quad*8+j]; B-frag: k[n=l16][d=c*32+quad*8+j]
//     (both row-contiguous loads straight from global, bf16-packed in reg)
//   C-layout: lane holds sc[h=quad*4+r][e=l16], r=0..3.
//   softmax over e: __shfl_xor butterflies within the 16-lane quad group.
//   PV: out[h=quad*4+r][d=l16*4..+3] = sum_e p[h][e]*v[e][d] in f32 VALU;
//     p[h][e] gathered by __shfl (src lane = quad*16+e, same register r);
//     v float4 from global (4-way lane broadcast, L1-served).
// ---------------------------------------------------------------------------
__global__ __launch_bounds__(256)
void attn_kernel(const float*  __restrict__ queries,   // (N,Sq,E) f32
                 const ushort* __restrict__ condfeat,  // (N,Sq,E) bf16
                 const float*  __restrict__ keys,      // (N,Skv,E) f32
                 const float*  __restrict__ values,    // (N,Skv,E) f32
                 const int*    __restrict__ mask,      // (N,Skv,16,16) i32
                 ushort* __restrict__ attout)          // (N,Skv,E) bf16
{
    const int wid  = threadIdx.x >> 6;
    const int pos  = blockIdx.x * 4 + wid;    // n*SKV + s2
    const int s2   = pos & 4095;
    const int n    = pos >> 12;
    const int lane = threadIdx.x & 63;
    const int quad = lane >> 4;
    const int l16  = lane & 15;

    // ---- load A-frag (cq) and B-frag (k) ----
    short8 aF[2], bF[2];
    if (s2 & 1) {
        const ushort* cp = condfeat + ((size_t)n * SQ + (s2 >> 1)) * EMB
                           + l16 * 64 + quad * 8;
        aF[0] = *(const short8*)cp;
        aF[1] = *(const short8*)(cp + 32);
    } else {
        const float* qp = queries + ((size_t)n * SQ + (s2 >> 1)) * EMB
                          + l16 * 64 + quad * 8;
        aF[0] = pack_bf16x8(*(const float4*)qp,        *(const float4*)(qp + 4));
        aF[1] = pack_bf16x8(*(const float4*)(qp + 32), *(const float4*)(qp + 36));
    }
    {
        const float* kp = keys + (size_t)pos * EMB + l16 * 64 + quad * 8;
        bF[0] = pack_bf16x8(*(const float4*)kp,        *(const float4*)(kp + 4));
        bF[1] = pack_bf16x8(*(const float4*)(kp + 32), *(const float4*)(kp + 36));
    }

    f32x4 sc = (f32x4){0.f, 0.f, 0.f, 0.f};
    sc = __builtin_amdgcn_mfma_f32_16x16x32_bf16(aF[0], bF[0], sc, 0, 0, 0);
    sc = __builtin_amdgcn_mfma_f32_16x16x32_bf16(aF[1], bF[1], sc, 0, 0, 0);

    // ---- mask + softmax (per r: row h=quad*4+r spread across l16 lanes) ----
    const int* mrow = mask + (size_t)pos * 256;
    float p[4];
#pragma unroll
    for (int r = 0; r < 4; ++r) {
        float s = sc[r] * 0.125f;                       // 1/sqrt(64)
        const int mv = mrow[(quad * 4 + r) * 16 + l16];
        s = (mv == 0) ? -1e20f : s;
        float mx = s;
#pragma unroll
        for (int d = 1; d < 16; d <<= 1)
            mx = fmaxf(mx, __shfl_xor(mx, d));
        const float ex = __expf(s - mx);                // all-masked row -> 1/16
        float sum = ex;
#pragma unroll
        for (int d = 1; d < 16; d <<= 1)
            sum += __shfl_xor(sum, d);
        p[r] = ex / sum;
    }

    // ---- PV in f32: out[h=quad*4+r][d=l16*4..+3] ----
    float4 acc[4];
#pragma unroll
    for (int r = 0; r < 4; ++r) acc[r] = (float4){0.f, 0.f, 0.f, 0.f};

    const float* vp = values + (size_t)pos * EMB + l16 * 4;
#pragma unroll
    for (int eh = 0; eh < 2; ++eh) {
        float4 vv[8];
#pragma unroll
        for (int j = 0; j < 8; ++j)
            vv[j] = *(const float4*)(vp + (eh * 8 + j) * 64);
#pragma unroll
        for (int r = 0; r < 4; ++r) {
#pragma unroll
            for (int j = 0; j < 8; ++j) {
                const float pe = __shfl(p[r], quad * 16 + eh * 8 + j);
                acc[r].x += pe * vv[j].x;
                acc[r].y += pe * vv[j].y;
                acc[r].z += pe * vv[j].z;
                acc[r].w += pe * vv[j].w;
            }
        }
    }

    // ---- store bf16 ----
    ushort* op = attout + (size_t)pos * EMB;
#pragma unroll
    for (int r = 0; r < 4; ++r) {
        ushort4 o;
        o.x = f2b(acc[r].x); o.y = f2b(acc[r].y);
        o.z = f2b(acc[r].z); o.w = f2b(acc[r].w);
        *(ushort4*)(op + (quad * 4 + r) * 64 + l16 * 4) = o;
    }
}

// ---------------------------------------------------------------------------
extern "C" void kernel_launch(void* const* d_in, const int* in_sizes, int n_in,
                              void* d_out, int out_size, void* d_ws, size_t ws_size,
                              hipStream_t stream)
{
    const float* values    = (const float*)d_in[0];
    const float* keys      = (const float*)d_in[1];
    const float* queries   = (const float*)d_in[2];
    const int*   mask      = (const int*)  d_in[3];
    const float* condition = (const float*)d_in[4];
    const float* Wc        = (const float*)d_in[5];
    const float* bc        = (const float*)d_in[6];
    const float* Wo        = (const float*)d_in[7];
    const float* bo        = (const float*)d_in[8];
    float* out = (float*)d_out;

    // workspace (48 MB total, liveness-aliased):
    //  [0,16MB)  condfeat bf16 (8192x1024)   live: gemm1 -> attn
    //  [16,48MB) attout  bf16 (16384x1024)   live: attn -> gemm3
    //  cond_bf (8MB) + Wc_bf (1MB) alias attout (dead before attn writes)
    //  Wo_bf (2MB) aliases condfeat (converted after attn)
    ushort* condfeat = (ushort*)d_ws;
    ushort* attout   = condfeat + (size_t)NB * SQ * EMB;
    ushort* cond_bf  = attout;
    ushort* Wc_bf    = attout + (size_t)NB * SQ * CDIM;
    ushort* Wo_bf    = condfeat;

    cvt_f32_bf16<<<(NB * SQ * CDIM / 4 + 255) / 256, 256, 0, stream>>>(
        condition, cond_bf, NB * SQ * CDIM / 4);
    cvt_f32_bf16<<<(EMB * CDIM / 4 + 255) / 256, 256, 0, stream>>>(
        Wc, Wc_bf, EMB * CDIM / 4);

    // 1) cond_feat = condition @ Wc^T + bc   (8192x1024, K=512) -> bf16
    {
        dim3 grid((NB * SQ) / 128, EMB / 128);
        gemm_bt_bias<ushort><<<grid, 256, 0, stream>>>(
            cond_bf, Wc_bf, bc, condfeat, NB * SQ, EMB, CDIM);
    }

    // 2) wave-per-position attention -> att_out (bf16)
    attn_kernel<<<(NB * SKV) / 4, 256, 0, stream>>>(
        queries, condfeat, keys, values, mask, attout);

    // convert Wo after attn (aliases dead condfeat)
    cvt_f32_bf16<<<(EMB * EMB / 4 + 255) / 256, 256, 0, stream>>>(
        Wo, Wo_bf, EMB * EMB / 4);

    // 3) out = att_out @ Wo^T + bo   (16384x1024, K=1024) -> f32
    {
        dim3 grid((NB * SKV) / 128, EMB / 128);
        gemm_bt_bias<float><<<grid, 256, 0, stream>>>(
            attout, Wo_bf, bo, out, NB * SKV, EMB, EMB);
    }
}

// Round 5
// 306.076 us; speedup vs baseline: 1.0101x; 1.0101x over previous
//
#include <hip/hip_runtime.h>
#include <hip/hip_bf16.h>
#include <type_traits>

// Problem constants: N=4, Sq=2048, Skv=4096, E=1024, H=16, D=64, C=512
// Float tensors are FP32 in global; mask int32; output fp32.
#define NB   4
#define SQ   2048
#define SKV  4096
#define EMB  1024
#define CDIM 512

typedef __attribute__((ext_vector_type(8))) short short8;
typedef __attribute__((ext_vector_type(4))) float f32x4;
typedef __attribute__((ext_vector_type(4))) _Float16 half4;

__device__ __forceinline__ float b2f(ushort u) {
    union { unsigned int i; float f; } v;
    v.i = ((unsigned int)u) << 16;
    return v.f;
}
__device__ __forceinline__ ushort f2b(float f) {
    union { float f; unsigned int i; } v; v.f = f;
    unsigned int x = v.i;
    return (ushort)((x + 0x7fffu + ((x >> 16) & 1u)) >> 16);   // RNE
}
__device__ __forceinline__ short8 pack_bf16x8(float4 a, float4 b) {
    union { short8 s; ushort u[8]; } r;
    r.u[0] = f2b(a.x); r.u[1] = f2b(a.y); r.u[2] = f2b(a.z); r.u[3] = f2b(a.w);
    r.u[4] = f2b(b.x); r.u[5] = f2b(b.y); r.u[6] = f2b(b.z); r.u[7] = f2b(b.w);
    return r.s;
}

// async global->LDS, 16B per lane; LDS dest = wave-uniform base + lane*16
__device__ __forceinline__ void glds16(const ushort* gp, ushort* lp) {
    __builtin_amdgcn_global_load_lds(
        (const __attribute__((address_space(1))) unsigned int*)gp,
        (__attribute__((address_space(3))) unsigned int*)lp,
        16, 0, 0);
}

// ---------------------------------------------------------------------------
// f32 -> bf16 bulk convert (memory-bound)
// ---------------------------------------------------------------------------
__global__ __launch_bounds__(256)
void cvt_f32_bf16(const float* __restrict__ in, ushort* __restrict__ out, int n4)
{
    const int i = blockIdx.x * 256 + threadIdx.x;
    if (i < n4) {
        float4 v = ((const float4*)in)[i];
        ushort4 o;
        o.x = f2b(v.x); o.y = f2b(v.y); o.z = f2b(v.z); o.w = f2b(v.w);
        ((ushort4*)out)[i] = o;
    }
}

// ---------------------------------------------------------------------------
// Pure-bf16 GEMM (m97 structure): C[m,n] = sum_k A[m,k]*B[n,k] + bias[n]
// 128x128 tile, BK=32, 4 waves x (4x4) mfma_f32_16x16x32_bf16,
// staging via global_load_lds width=16.  (unchanged — passed rounds 3/4)
// ---------------------------------------------------------------------------
template <typename OT>
__global__ __launch_bounds__(256)
void gemm_bt_bias(const ushort* __restrict__ A, const ushort* __restrict__ B,
                  const float* __restrict__ bias, OT* __restrict__ C,
                  int M, int Nn, int K)
{
    __shared__ __attribute__((aligned(16))) ushort As[128 * 32];
    __shared__ __attribute__((aligned(16))) ushort Bs[128 * 32];

    const int tid  = threadIdx.x;
    const int wave = tid >> 6;
    const int lane = tid & 63;
    const int quad = lane >> 4;
    const int l16  = lane & 15;
    const int wr   = wave >> 1;
    const int wc   = wave & 1;

    const long mBase = (long)blockIdx.x * 128;
    const long nBase = (long)blockIdx.y * 128;

    const ushort* Ablk = A + mBase * K;
    const ushort* Bblk = B + nBase * K;

    const int lr = lane >> 2;
    const int lc = (lane & 3) * 8;
    const int c0 = wave * 2, c1 = wave * 2 + 1;
    const ushort* aG0 = Ablk + (long)(c0 * 16 + lr) * K + lc;
    const ushort* aG1 = Ablk + (long)(c1 * 16 + lr) * K + lc;
    const ushort* bG0 = Bblk + (long)(c0 * 16 + lr) * K + lc;
    const ushort* bG1 = Bblk + (long)(c1 * 16 + lr) * K + lc;
    ushort* aL0 = As + c0 * 512;
    ushort* aL1 = As + c1 * 512;
    ushort* bL0 = Bs + c0 * 512;
    ushort* bL1 = Bs + c1 * 512;

    f32x4 acc[4][4];
#pragma unroll
    for (int i = 0; i < 4; ++i)
#pragma unroll
        for (int j = 0; j < 4; ++j)
            acc[i][j] = (f32x4){0.f, 0.f, 0.f, 0.f};

    for (int k0 = 0; k0 < K; k0 += 32) {
        __syncthreads();
        glds16(aG0 + k0, aL0);
        glds16(aG1 + k0, aL1);
        glds16(bG0 + k0, bL0);
        glds16(bG1 + k0, bL1);
        __syncthreads();

        short8 af[4], bfr[4];
#pragma unroll
        for (int mt = 0; mt < 4; ++mt)
            af[mt] = *(const short8*)(As + (wr * 64 + mt * 16 + l16) * 32 + quad * 8);
#pragma unroll
        for (int nt = 0; nt < 4; ++nt)
            bfr[nt] = *(const short8*)(Bs + (wc * 64 + nt * 16 + l16) * 32 + quad * 8);

#pragma unroll
        for (int mt = 0; mt < 4; ++mt)
#pragma unroll
            for (int nt = 0; nt < 4; ++nt)
                acc[mt][nt] = __builtin_amdgcn_mfma_f32_16x16x32_bf16(
                    af[mt], bfr[nt], acc[mt][nt], 0, 0, 0);
    }

#pragma unroll
    for (int mt = 0; mt < 4; ++mt) {
#pragma unroll
        for (int nt = 0; nt < 4; ++nt) {
            const long n = nBase + wc * 64 + nt * 16 + l16;
            const float bv = bias[n];
#pragma unroll
            for (int r = 0; r < 4; ++r) {
                const long m = mBase + wr * 64 + mt * 16 + quad * 4 + r;
                if constexpr (std::is_same<OT, float>::value)
                    C[m * Nn + n] = acc[mt][nt][r] + bv;
                else
                    C[m * Nn + n] = f2b(acc[mt][nt][r] + bv);
            }
        }
    }
}

// ---------------------------------------------------------------------------
// Attention: ONE WAVE per (n, s2); 4 waves/block. Zero LDS-tiles, zero barriers.
//   Scores TRANSPOSED: S^T = mfma(kF, qF) twice (K-dim = D = 64) so a lane
//   holds S[h=l16][e=quad*4+r] — the full softmax row is 4 regs x 4 lanes:
//   reduction = 3 VALU + __shfl_xor(16) + __shfl_xor(32) (2 chained ops only).
//   P then sits EXACTLY in the A-fragment layout of mfma_f32_16x16x16f16
//   (A[m=l16][k=quad*4+j]) -> PV = 4 MFMAs over dtiles, V as f16 B-frags
//   (B[n=l16][k=quad*4+j] <- V[e=quad*4+j][dtile*16+l16]).
//   All global loads hoisted to the top for max VMEM overlap.
// ---------------------------------------------------------------------------
__global__ __launch_bounds__(256)
void attn_kernel(const float*  __restrict__ queries,   // (N,Sq,E) f32
                 const ushort* __restrict__ condfeat,  // (N,Sq,E) bf16
                 const float*  __restrict__ keys,      // (N,Skv,E) f32
                 const float*  __restrict__ values,    // (N,Skv,E) f32
                 const int*    __restrict__ mask,      // (N,Skv,16,16) i32
                 ushort* __restrict__ attout)          // (N,Skv,E) bf16
{
    const int wid  = threadIdx.x >> 6;
    const int pos  = blockIdx.x * 4 + wid;    // n*SKV + s2
    const int s2   = pos & 4095;
    const int n    = pos >> 12;
    const int lane = threadIdx.x & 63;
    const int quad = lane >> 4;
    const int l16  = lane & 15;

    // ================= hoisted global loads =================
    // q / cq  (row l16, cols quad*8.. and +32..)
    short8 qF[2];
    float4 qf[4];
    const bool odd = (s2 & 1);
    if (odd) {
        const ushort* cp = condfeat + ((size_t)n * SQ + (s2 >> 1)) * EMB
                           + l16 * 64 + quad * 8;
        qF[0] = *(const short8*)cp;
        qF[1] = *(const short8*)(cp + 32);
    } else {
        const float* qp = queries + ((size_t)n * SQ + (s2 >> 1)) * EMB
                          + l16 * 64 + quad * 8;
        qf[0] = *(const float4*)qp;        qf[1] = *(const float4*)(qp + 4);
        qf[2] = *(const float4*)(qp + 32); qf[3] = *(const float4*)(qp + 36);
    }
    // k (row l16, cols quad*8.. / +32..)
    const float* kp = keys + (size_t)pos * EMB + l16 * 64 + quad * 8;
    float4 kf0 = *(const float4*)kp,        kf1 = *(const float4*)(kp + 4);
    float4 kf2 = *(const float4*)(kp + 32), kf3 = *(const float4*)(kp + 36);
    // v: V[e=quad*4+j][dtile*16+l16]  (16 scalar f32, fully covering 16x64)
    const float* vb = values + (size_t)pos * EMB;
    float vf[4][4];
#pragma unroll
    for (int j = 0; j < 4; ++j)
#pragma unroll
        for (int dt = 0; dt < 4; ++dt)
            vf[j][dt] = vb[(quad * 4 + j) * 64 + dt * 16 + l16];
    // mask: one coalesced int4 per lane = mask[h=l16][e=quad*4 .. +3]
    const int4 m4 = *(const int4*)(mask + (size_t)pos * 256 + l16 * 16 + quad * 4);

    // ================= QK^T (transposed) =================
    short8 kF0 = pack_bf16x8(kf0, kf1);
    short8 kF1 = pack_bf16x8(kf2, kf3);
    if (!odd) {
        qF[0] = pack_bf16x8(qf[0], qf[1]);
        qF[1] = pack_bf16x8(qf[2], qf[3]);
    }
    f32x4 st = (f32x4){0.f, 0.f, 0.f, 0.f};
    st = __builtin_amdgcn_mfma_f32_16x16x32_bf16(kF0, qF[0], st, 0, 0, 0);
    st = __builtin_amdgcn_mfma_f32_16x16x32_bf16(kF1, qF[1], st, 0, 0, 0);
    // lane now holds S[h=l16][e=quad*4+r] in st[r]

    // ================= mask + row softmax =================
    const int mv[4] = {m4.x, m4.y, m4.z, m4.w};
    float s[4];
#pragma unroll
    for (int r = 0; r < 4; ++r) {
        float v = st[r] * 0.125f;                 // 1/sqrt(64)
        s[r] = (mv[r] == 0) ? -1e20f : v;
    }
    float mx = fmaxf(fmaxf(s[0], s[1]), fmaxf(s[2], s[3]));
    mx = fmaxf(mx, __shfl_xor(mx, 16));
    mx = fmaxf(mx, __shfl_xor(mx, 32));
    float ex[4];
    float sum = 0.f;
#pragma unroll
    for (int r = 0; r < 4; ++r) { ex[r] = __expf(s[r] - mx); sum += ex[r]; }
    sum += __shfl_xor(sum, 16);
    sum += __shfl_xor(sum, 32);
    const float inv = 1.f / sum;                  // all-masked row -> 1/16 each

    // ================= PV via f16 MFMA =================
    half4 pA;
#pragma unroll
    for (int r = 0; r < 4; ++r) pA[r] = (_Float16)(ex[r] * inv);

    f32x4 oacc[4];
#pragma unroll
    for (int dt = 0; dt < 4; ++dt) {
        half4 vF;
#pragma unroll
        for (int j = 0; j < 4; ++j) vF[j] = (_Float16)vf[j][dt];
        f32x4 z = (f32x4){0.f, 0.f, 0.f, 0.f};
        oacc[dt] = __builtin_amdgcn_mfma_f32_16x16x16f16(pA, vF, z, 0, 0, 0);
    }
    // lane holds out[h=quad*4+r][dtile*16+l16] in oacc[dt][r]

    // ================= store bf16 =================
    ushort* op = attout + (size_t)pos * EMB;
#pragma unroll
    for (int r = 0; r < 4; ++r)
#pragma unroll
        for (int dt = 0; dt < 4; ++dt)
            op[(quad * 4 + r) * 64 + dt * 16 + l16] = f2b(oacc[dt][r]);
}

// ---------------------------------------------------------------------------
extern "C" void kernel_launch(void* const* d_in, const int* in_sizes, int n_in,
                              void* d_out, int out_size, void* d_ws, size_t ws_size,
                              hipStream_t stream)
{
    const float* values    = (const float*)d_in[0];
    const float* keys      = (const float*)d_in[1];
    const float* queries   = (const float*)d_in[2];
    const int*   mask      = (const int*)  d_in[3];
    const float* condition = (const float*)d_in[4];
    const float* Wc        = (const float*)d_in[5];
    const float* bc        = (const float*)d_in[6];
    const float* Wo        = (const float*)d_in[7];
    const float* bo        = (const float*)d_in[8];
    float* out = (float*)d_out;

    // workspace (48 MB total, liveness-aliased):
    //  [0,16MB)  condfeat bf16 (8192x1024)   live: gemm1 -> attn
    //  [16,48MB) attout  bf16 (16384x1024)   live: attn -> gemm3
    //  cond_bf (8MB) + Wc_bf (1MB) alias attout (dead before attn writes)
    //  Wo_bf (2MB) aliases condfeat (converted after attn)
    ushort* condfeat = (ushort*)d_ws;
    ushort* attout   = condfeat + (size_t)NB * SQ * EMB;
    ushort* cond_bf  = attout;
    ushort* Wc_bf    = attout + (size_t)NB * SQ * CDIM;
    ushort* Wo_bf    = condfeat;

    cvt_f32_bf16<<<(NB * SQ * CDIM / 4 + 255) / 256, 256, 0, stream>>>(
        condition, cond_bf, NB * SQ * CDIM / 4);
    cvt_f32_bf16<<<(EMB * CDIM / 4 + 255) / 256, 256, 0, stream>>>(
        Wc, Wc_bf, EMB * CDIM / 4);

    // 1) cond_feat = condition @ Wc^T + bc   (8192x1024, K=512) -> bf16
    {
        dim3 grid((NB * SQ) / 128, EMB / 128);
        gemm_bt_bias<ushort><<<grid, 256, 0, stream>>>(
            cond_bf, Wc_bf, bc, condfeat, NB * SQ, EMB, CDIM);
    }

    // 2) wave-per-position attention -> att_out (bf16)
    attn_kernel<<<(NB * SKV) / 4, 256, 0, stream>>>(
        queries, condfeat, keys, values, mask, attout);

    // convert Wo after attn (aliases dead condfeat)
    cvt_f32_bf16<<<(EMB * EMB / 4 + 255) / 256, 256, 0, stream>>>(
        Wo, Wo_bf, EMB * EMB / 4);

    // 3) out = att_out @ Wo^T + bo   (16384x1024, K=1024) -> f32
    {
        dim3 grid((NB * SKV) / 128, EMB / 128);
        gemm_bt_bias<float><<<grid, 256, 0, stream>>>(
            attout, Wo_bf, bo, out, NB * SKV, EMB, EMB);
    }
}